// Round 11
// baseline (313.880 us; speedup 1.0000x reference)
//
#include <hip/hip_runtime.h>
#include <stdint.h>
#include <type_traits>

// Problem constants
#define BB  4
#define SS  2048
#define DD  1024
#define HH  16
#define HDD 64

typedef __attribute__((ext_vector_type(8))) short s16x8;   // 8 bf16 (4 VGPRs)
typedef __attribute__((ext_vector_type(4))) float f32x4;   // MFMA C/D

__device__ inline short f2bf(float f) {
    union { float f; unsigned int u; } v; v.f = f;
    unsigned int r = (v.u + 0x7fffu + ((v.u >> 16) & 1u)) >> 16; // RNE
    return (short)r;
}

__device__ inline float bf2f(short s) {
    union { unsigned int u; float f; } v;
    v.u = ((unsigned int)(unsigned short)s) << 16;
    return v.f;
}

__device__ inline unsigned int pk2(float a, float b) {
    return (unsigned int)(unsigned short)f2bf(a) |
           ((unsigned int)(unsigned short)f2bf(b) << 16);
}

#define GLL(gp, lp) __builtin_amdgcn_global_load_lds( \
    (const __attribute__((address_space(1))) void*)(gp), \
    (__attribute__((address_space(3))) void*)(lp), 16, 0, 0)

// Raw barrier: orders this wave's LDS ops (lgkmcnt) then syncs. Does NOT
// drain vmcnt -> global_load_lds prefetch stays in flight across it.
__device__ inline void lds_barrier() {
    asm volatile("s_waitcnt lgkmcnt(0)" ::: "memory");
    __builtin_amdgcn_sched_barrier(0);
    __builtin_amdgcn_s_barrier();
    __builtin_amdgcn_sched_barrier(0);
}

// ---------------- fp32 -> bf16 cast (n % 8 == 0) ----------------
__global__ void cvt_kernel(const float* __restrict__ src, short* __restrict__ dst, int n) {
    int i = (blockIdx.x * 256 + threadIdx.x) * 8;
    if (i >= n) return;
    const float4* s = (const float4*)(src + i);
    float4 a = s[0], b = s[1];
    s16x8 o;
    o[0]=f2bf(a.x); o[1]=f2bf(a.y); o[2]=f2bf(a.z); o[3]=f2bf(a.w);
    o[4]=f2bf(b.x); o[5]=f2bf(b.y); o[6]=f2bf(b.z); o[7]=f2bf(b.w);
    *(s16x8*)(dst + i) = o;
}

// ---------------- GEMM C = A @ B^T + bias (256x256 8-wave, phase-interleaved) ------
// Rounds 8/10 pinned the 128-tile 2-phase structure at ~21% MfmaUtil (lockstep
// stage->vmcnt->barrier critical path). This is the T3+T4 rework at 256x256:
//   - 8 waves (2M x 4N), per-wave 128x64 output, acc[8][4]: 43.7 FLOP per LDS byte
//     (vs 32 at 64x64) -> LDS read pipe no longer oversubscribes MFMA.
//   - Per K-tile (BK=64): 4 quadrant-phases. Each phase: {4 A-frag ds_read_b128;
//     (q==0: +2 GLL half-tiles of A(j+1); q==1: +2 of B(j+1)); s_barrier;
//     lgkmcnt(0); setprio(1); 16 MFMA; setprio(0); s_barrier}. B-frags (8 reads)
//     hoisted once per tile. The barrier pairs make waves alternate mem/MFMA
//     windows (the m201 role-split mechanism).
//   - Buffer rotation (race-free, verified): K-tile j lives in dbuf[j&1]; tile j's
//     phases stage tile j+1 into dbuf^1, whose prior content (tile j-1) was last
//     read before tile j-1's boundary barrier. Boundary: own-wave vmcnt(0) +
//     barrier; loads were issued >=2 phases (~400cy) earlier -> near-zero stall.
// LDS 128 KiB -> 1 block/CU; launch_bounds(512,2) caps VGPR at 256 (usage ~200).
template<int EPI>
__global__ __launch_bounds__(512, 2)
void gemm256(const short* __restrict__ A, const short* __restrict__ Bw,
             const float* __restrict__ bias, float* __restrict__ Cf,
             short* __restrict__ Qo, short* __restrict__ Ko, short* __restrict__ Vo,
             int M, int N, int K, int nbx)
{
    __shared__ short lsA[2][256 * 64];     // [dbuf][row][col granule-swizzled]
    __shared__ short lsB[2][256 * 64];

    const int tid  = threadIdx.x;
    const int w    = tid >> 6, lane = tid & 63;
    const int quad = lane >> 4, l15 = lane & 15;
    const int wm = w >> 2, wn = w & 3;          // 2M x 4N wave grid
    const int cpx = gridDim.x >> 3;             // T1 XCD swizzle (grid % 8 == 0)
    const int swz = (blockIdx.x & 7) * cpx + (blockIdx.x >> 3);
    const int m0 = (swz / nbx) * 256, n0 = (swz % nbx) * 256;
    const int grow = lane >> 3;                 // row-within-octet this lane covers
    const int gcol = ((lane & 7) ^ grow) * 8;   // inverse-swizzled source col (shorts)
    const int l7 = l15 & 7;

    f32x4 acc[8][4] = {};

    // stage one half-tile (128 rows x 64 cols) of K-tile kt into dbuf[kt&1].
    // part p: 0 = A rows 0-127, 1 = A rows 128-255, 2 = B rows 0-127, 3 = B rows 128-255
    auto stage_half = [&](int kt, int p) {
        const short* src = (p < 2) ? A : Bw;
        const int g0 = ((p < 2) ? m0 : n0) + (p & 1) * 128;
        short* dst = (p < 2) ? &lsA[kt & 1][(p & 1) * 128 * 64]
                             : &lsB[kt & 1][(p & 1) * 128 * 64];
#pragma unroll
        for (int jj = 0; jj < 2; ++jj) {
            int c = w * 2 + jj;                 // chunk 0..15 (8 rows x 64 cols = 1 KB)
            GLL(src + (size_t)(g0 + c * 8 + grow) * K + kt * 64 + gcol,
                dst + c * 512);
        }
    };

    const int NT = K >> 6;                      // BK=64 K-tiles (16 here)

    // prologue: K-tile 0 staged + drained
#pragma unroll
    for (int p = 0; p < 4; ++p) stage_half(0, p);
    asm volatile("s_waitcnt vmcnt(0)" ::: "memory");
    __builtin_amdgcn_sched_barrier(0);
    __builtin_amdgcn_s_barrier();
    __builtin_amdgcn_sched_barrier(0);

    for (int j = 0; j < NT; ++j) {
        const int d = j & 1;

        // B-fragments for the whole K-tile (wave's 64-col slice x K=64)
        s16x8 bfr[4][2];
#pragma unroll
        for (int nf = 0; nf < 4; ++nf)
#pragma unroll
            for (int ks = 0; ks < 2; ++ks)
                bfr[nf][ks] = *(const s16x8*)&lsB[d][(wn * 64 + nf * 16 + l15) * 64 +
                                                    (((ks * 4 + quad) ^ l7) * 8)];

#pragma unroll
        for (int q = 0; q < 4; ++q) {
            // A-fragments for quadrant q (rows wm*128 + q*32 .. +32)
            s16x8 af[2][2];
#pragma unroll
            for (int mf = 0; mf < 2; ++mf)
#pragma unroll
                for (int ks = 0; ks < 2; ++ks)
                    af[mf][ks] = *(const s16x8*)&lsA[d][(wm * 128 + q * 32 + mf * 16 + l15) * 64 +
                                                       (((ks * 4 + quad) ^ l7) * 8)];
            // stage next K-tile early (2 half-tiles per mem-window, phases 0 and 1)
            if (j + 1 < NT) {
                if (q == 0)      { stage_half(j + 1, 0); stage_half(j + 1, 1); }
                else if (q == 1) { stage_half(j + 1, 2); stage_half(j + 1, 3); }
            }
            __builtin_amdgcn_s_barrier();        // end of mem window
            asm volatile("s_waitcnt lgkmcnt(0)" ::: "memory");
            __builtin_amdgcn_sched_barrier(0);
            __builtin_amdgcn_s_setprio(1);
#pragma unroll
            for (int ks = 0; ks < 2; ++ks)
#pragma unroll
                for (int mf = 0; mf < 2; ++mf)
#pragma unroll
                    for (int nf = 0; nf < 4; ++nf)
                        acc[q * 2 + mf][nf] = __builtin_amdgcn_mfma_f32_16x16x32_bf16(
                            af[mf][ks], bfr[nf][ks], acc[q * 2 + mf][nf], 0, 0, 0);
            __builtin_amdgcn_s_setprio(0);
            __builtin_amdgcn_s_barrier();        // end of compute window
            __builtin_amdgcn_sched_barrier(0);
        }

        // tile boundary: this wave's 8 GLLs (issued phases 0-1) must have landed
        // before any wave reads dbuf^1 next tile; barrier extends to all waves.
        asm volatile("s_waitcnt vmcnt(0)" ::: "memory");
        __builtin_amdgcn_sched_barrier(0);
        __builtin_amdgcn_s_barrier();
        __builtin_amdgcn_sched_barrier(0);
    }

    if (EPI == 0) {
#pragma unroll
        for (int a = 0; a < 8; ++a) {
            int row = m0 + wm * 128 + (a >> 1) * 32 + (a & 1) * 16 + quad * 4;
#pragma unroll
            for (int nf = 0; nf < 4; ++nf) {
                int col = n0 + wn * 64 + nf * 16 + l15;
                float bv = bias[col];
#pragma unroll
                for (int r = 0; r < 4; ++r)
                    Cf[(size_t)(row + r) * N + col] = acc[a][nf][r] + bv;
            }
        }
    } else {
#pragma unroll
        for (int a = 0; a < 8; ++a) {
            int row = m0 + wm * 128 + (a >> 1) * 32 + (a & 1) * 16 + quad * 4;
#pragma unroll
            for (int nf = 0; nf < 4; ++nf) {
                int col = n0 + wn * 64 + nf * 16 + l15;
                float bv = bias[col];
                int sel = col >> 10, h = (col >> 6) & 15, hd = col & 63;
#pragma unroll
                for (int r = 0; r < 4; ++r) {
                    int rr = row + r;
                    int b = rr >> 11, s = rr & 2047;
                    short val = f2bf(acc[a][nf][r] + bv);
                    if (sel == 0)      Qo[(((size_t)b * HH + h) * SS + s) * HDD + hd] = val;
                    else if (sel == 1) Ko[(((size_t)b * HH + h) * SS + s) * HDD + hd] = val;
                    else               Vo[(((size_t)b * HH + h) * HDD + hd) * SS + s] = val;
                }
            }
        }
    }
}

// ---------------- causal flash attention (swapped QK^T, in-lane softmax) -----------
// (unchanged from round 10: <96 µs, 0 bank conflicts)
__global__ __launch_bounds__(256, 2)
void attn_kernel(const short* __restrict__ Q, const short* __restrict__ Kb,
                 const short* __restrict__ Vb, const int* __restrict__ mask,
                 short* __restrict__ O)
{
    __shared__ short lsK[2][64 * 64];      // [buf][key][hd] linear (GLL), src-swizzled
    __shared__ short lsV[2][64 * 64];      // [buf][hd][key] linear (GLL), src-swizzled
    __shared__ short lsP[4][32 * 64];      // per-wave P [qrow 32][key 64], granule-XOR
    __shared__ short lsM[SS];              // mask additive, bf16 (0 or -1e30)

    const int tid  = threadIdx.x;
    const int w    = tid >> 6, lane = tid & 63;
    const int quad = lane >> 4, l15 = lane & 15;
    const int bx = blockIdx.x, bh = blockIdx.y;
    const int b = bh >> 4;
    const size_t baseQK = (size_t)bh * SS * HDD;
    const size_t baseV  = (size_t)bh * HDD * SS;
    const float SC = 0.18033688f;          // (1/8) * log2(e)
    const int grow = lane >> 3;            // GLL: row-within-8 covered by this lane
    const int gcol = ((lane & 7) ^ grow) * 8;  // GLL: inverse-swizzled source col (shorts)
    const int l7 = l15 & 7;

    // stage mask -> lsM once (visible after first lds_barrier)
    {
        const int4* mp = (const int4*)(mask + b * SS);
        int4 a = mp[tid * 2], c = mp[tid * 2 + 1];
        const short NEG = f2bf(-1e30f);
        s16x8 mo;
        mo[0] = a.x ? (short)0 : NEG; mo[1] = a.y ? (short)0 : NEG;
        mo[2] = a.z ? (short)0 : NEG; mo[3] = a.w ? (short)0 : NEG;
        mo[4] = c.x ? (short)0 : NEG; mo[5] = c.y ? (short)0 : NEG;
        mo[6] = c.z ? (short)0 : NEG; mo[7] = c.w ? (short)0 : NEG;
        *(s16x8*)&lsM[tid * 8] = mo;
    }

    // issue tile (kv0) K/V global->LDS DMA into buffer buf: 4 GLL per wave
    auto issue = [&](int kv0, int buf) {
#pragma unroll
        for (int jj = 0; jj < 2; ++jj) {
            int row = w * 16 + jj * 8 + grow;                  // key row
            GLL(Kb + baseQK + (size_t)(kv0 + row) * HDD + gcol,
                &lsK[buf][(w * 2 + jj) * 512]);
        }
#pragma unroll
        for (int jj = 0; jj < 2; ++jj) {
            int row = w * 16 + jj * 8 + grow;                  // hd row
            GLL(Vb + baseV + (size_t)row * SS + kv0 + gcol,
                &lsV[buf][(w * 2 + jj) * 512]);
        }
    };

    for (int t = 0; t < 2; ++t) {
        const int qb = t ? bx : (15 - bx);  // heavy q-tile first
        const int q0 = qb * 128;
        const int qw0 = q0 + w * 32;        // this wave's first q-row

        s16x8 aq[2][2];
#pragma unroll
        for (int s = 0; s < 2; ++s)
#pragma unroll
            for (int ks = 0; ks < 2; ++ks)
                aq[s][ks] = *(const s16x8*)(Q + baseQK +
                    (size_t)(qw0 + s * 16 + l15) * HDD + ks * 32 + quad * 8);

        float m_r[2], l_r[2];
        f32x4 o_acc[2][4] = {};
#pragma unroll
        for (int s = 0; s < 2; ++s) { m_r[s] = -1e30f; l_r[s] = 0.f; }

        const int ntiles = 2 * qb + 2;      // 64-key tiles; last two are diagonal

        lds_barrier();                      // prev t's reads done / mask visible
        issue(0, 0);

        auto tile = [&](auto CC, int kv0, int buf, int kvn) {
            constexpr bool CAUS = decltype(CC)::value;

            lds_barrier();                  // A: all waves done reading buf^1
            if (kvn >= 0) issue(kvn, buf ^ 1);

            // mask additive: 4 consecutive k per nt (8B broadcast-friendly read)
            float madd[4][4];
#pragma unroll
            for (int nt = 0; nt < 4; ++nt) {
                uint2 mw4 = *(const uint2*)&lsM[kv0 + nt * 16 + quad * 4];
                madd[nt][0] = bf2f((short)(mw4.x & 0xffff));
                madd[nt][1] = bf2f((short)(mw4.x >> 16));
                madd[nt][2] = bf2f((short)(mw4.y & 0xffff));
                madd[nt][3] = bf2f((short)(mw4.y >> 16));
            }

            if (kvn >= 0) asm volatile("s_waitcnt vmcnt(4)" ::: "memory");
            else          asm volatile("s_waitcnt vmcnt(0)" ::: "memory");
            __builtin_amdgcn_sched_barrier(0);
            __builtin_amdgcn_s_barrier();   // B: all waves' GLLs for buf landed
            __builtin_amdgcn_sched_barrier(0);

            // S^T = K Q^T : D[key][q]; lane holds q=l15, key=kv0+nt*16+quad*4+r
            f32x4 sv[2][4];
#pragma unroll
            for (int s = 0; s < 2; ++s)
#pragma unroll
                for (int nt = 0; nt < 4; ++nt) sv[s][nt] = f32x4{};
#pragma unroll
            for (int ks = 0; ks < 2; ++ks)
#pragma unroll
                for (int nt = 0; nt < 4; ++nt) {
                    s16x8 kf = *(const s16x8*)&lsK[buf][(nt * 16 + l15) * 64 +
                                                       (((ks * 4 + quad) ^ l7) * 8)];
#pragma unroll
                    for (int s = 0; s < 2; ++s)
                        sv[s][nt] = __builtin_amdgcn_mfma_f32_16x16x32_bf16(
                                        kf, aq[s][ks], sv[s][nt], 0, 0, 0);
                }

            // scale + key-mask + causal (k now lane-indexed, q = l15)
#pragma unroll
            for (int s = 0; s < 2; ++s) {
                const int qg = qw0 + s * 16 + l15;
#pragma unroll
                for (int nt = 0; nt < 4; ++nt) {
                    const int kg0 = kv0 + nt * 16 + quad * 4;
#pragma unroll
                    for (int r = 0; r < 4; ++r) {
                        float scv = sv[s][nt][r] * SC + madd[nt][r];
                        if (CAUS && kg0 + r > qg) scv = -1e30f;
                        sv[s][nt][r] = scv;
                    }
                }
            }

            // row max over keys: 16 in-lane + cross-quad (2 shfl)
            float rm[2];
#pragma unroll
            for (int s = 0; s < 2; ++s) {
                float v = fmaxf(fmaxf(fmaxf(sv[s][0][0], sv[s][0][1]),
                                      fmaxf(sv[s][0][2], sv[s][0][3])),
                                fmaxf(fmaxf(sv[s][1][0], sv[s][1][1]),
                                      fmaxf(sv[s][1][2], sv[s][1][3])));
                float v2 = fmaxf(fmaxf(fmaxf(sv[s][2][0], sv[s][2][1]),
                                       fmaxf(sv[s][2][2], sv[s][2][3])),
                                 fmaxf(fmaxf(sv[s][3][0], sv[s][3][1]),
                                       fmaxf(sv[s][3][2], sv[s][3][3])));
                v = fmaxf(v, v2);
                v = fmaxf(v, __shfl_xor(v, 16));
                v = fmaxf(v, __shfl_xor(v, 32));
                rm[s] = v;
            }
            // T13 defer-max: rescale only when some row's max grew > 8 (log2 domain)
            float need = fmaxf(rm[0] - m_r[0], rm[1] - m_r[1]);
            if (!__all(need <= 8.0f)) {
#pragma unroll
                for (int s = 0; s < 2; ++s) {
                    float nm = fmaxf(m_r[s], rm[s]);
                    float al = __builtin_amdgcn_exp2f(m_r[s] - nm);
                    m_r[s] = nm;
                    l_r[s] *= al;
#pragma unroll
                    for (int r = 0; r < 4; ++r) {
                        float alq = __shfl(al, (quad << 2) + r + (lane & 48));
#pragma unroll
                        for (int ht = 0; ht < 4; ++ht)
                            o_acc[s][ht][r] *= alq;
                    }
                }
            }
            // P = exp2(S - m); per-lane partial l (cross-quad sum at epilogue)
#pragma unroll
            for (int s = 0; s < 2; ++s) {
                float rs = 0.f;
#pragma unroll
                for (int nt = 0; nt < 4; ++nt)
#pragma unroll
                    for (int r = 0; r < 4; ++r) {
                        float p = __builtin_amdgcn_exp2f(sv[s][nt][r] - m_r[s]);
                        sv[s][nt][r] = p;
                        rs += p;
                    }
                l_r[s] += rs;
            }

            // P -> wave-private buffer: 4 consecutive k per lane = 1 ds_write_b64
            // granule g8=(nt*2+(quad>>1))^(l15&7), half quad&1 == reader's (k2*4+quad)^l7
            short* lsPw = lsP[w];
#pragma unroll
            for (int s = 0; s < 2; ++s)
#pragma unroll
                for (int nt = 0; nt < 4; ++nt) {
                    uint2 pw;
                    pw.x = pk2(sv[s][nt][0], sv[s][nt][1]);
                    pw.y = pk2(sv[s][nt][2], sv[s][nt][3]);
                    int row = s * 16 + l15;
                    int g8 = (nt * 2 + (quad >> 1)) ^ l7;
                    *(uint2*)&lsPw[row * 64 + (g8 << 3) + ((quad & 1) << 2)] = pw;
                }
            asm volatile("s_waitcnt lgkmcnt(0)" ::: "memory");
            __builtin_amdgcn_sched_barrier(0);

            // O += P V (ap read identical to round 8; V read unchanged)
            s16x8 ap[2][2];
#pragma unroll
            for (int s = 0; s < 2; ++s)
#pragma unroll
                for (int k2 = 0; k2 < 2; ++k2)
                    ap[s][k2] = *(const s16x8*)&lsPw[(s * 16 + l15) * 64 +
                                                     (((k2 * 4 + quad) ^ l7) << 3)];
#pragma unroll
            for (int ht = 0; ht < 4; ++ht)
#pragma unroll
                for (int k2 = 0; k2 < 2; ++k2) {
                    s16x8 vf = *(const s16x8*)&lsV[buf][(ht * 16 + l15) * 64 +
                                                        (((k2 * 4 + quad) ^ l7) * 8)];
#pragma unroll
                    for (int s = 0; s < 2; ++s)
                        o_acc[s][ht] = __builtin_amdgcn_mfma_f32_16x16x32_bf16(
                                           ap[s][k2], vf, o_acc[s][ht], 0, 0, 0);
                }
        };

        for (int kt = 0; kt < ntiles; ++kt) {
            const int kvn = (kt + 1 < ntiles) ? (kt + 1) * 64 : -1;
            if (kt >= 2 * qb) tile(std::true_type{},  kt * 64, kt & 1, kvn);
            else              tile(std::false_type{}, kt * 64, kt & 1, kvn);
        }

        // epilogue: sum l across quads, redistribute to o_acc rows, write O
        const int hcol = (bh & 15) * HDD;
#pragma unroll
        for (int s = 0; s < 2; ++s) {
            float ls = l_r[s];
            ls += __shfl_xor(ls, 16);
            ls += __shfl_xor(ls, 32);      // full row-sum for q = l15
#pragma unroll
            for (int r = 0; r < 4; ++r) {
                float lq = __shfl(ls, (quad << 2) + r + (lane & 48));
                float inv = 1.0f / lq;
                int srow = qw0 + s * 16 + quad * 4 + r;
                size_t base = ((size_t)b * SS + srow) * DD + hcol;
#pragma unroll
                for (int ht = 0; ht < 4; ++ht)
                    O[base + ht * 16 + l15] = f2bf(o_acc[s][ht][r] * inv);
            }
        }
    }
}

// ---------------- launch ----------------
extern "C" void kernel_launch(void* const* d_in, const int* in_sizes, int n_in,
                              void* d_out, int out_size, void* d_ws, size_t ws_size,
                              hipStream_t stream) {
    const float* x     = (const float*)d_in[0];
    const int*   mask  = (const int*)d_in[1];
    const float* qkv_w = (const float*)d_in[2];
    const float* qkv_b = (const float*)d_in[3];
    const float* out_w = (const float*)d_in[4];
    const float* out_b = (const float*)d_in[5];
    float* out = (float*)d_out;

    const size_t M1 = (size_t)BB * SS;       // 8192
    short* ws  = (short*)d_ws;
    short* xb  = ws;
    short* qwb = xb  + M1 * DD;
    short* owb = qwb + (size_t)3 * DD * DD;
    short* Qb  = owb + (size_t)DD * DD;
    short* Kb  = Qb  + M1 * DD;
    short* Vb  = Kb  + M1 * DD;
    short* Ob  = Vb  + M1 * DD;

    cvt_kernel<<<(int)(M1 * DD / 8 / 256), 256, 0, stream>>>(x, xb, (int)(M1 * DD));
    cvt_kernel<<<3 * DD * DD / 8 / 256, 256, 0, stream>>>(qkv_w, qwb, 3 * DD * DD);
    cvt_kernel<<<DD * DD / 8 / 256, 256, 0, stream>>>(out_w, owb, DD * DD);

    // qkv: M=8192, N=3072 -> 32 x 12 = 384 blocks (1/CU, 1.5 rounds)
    gemm256<1><<<384, 512, 0, stream>>>(xb, qwb, qkv_b, nullptr,
                                        Qb, Kb, Vb, 8192, 3072, 1024, 12);
    attn_kernel<<<dim3(8, BB * HH), 256, 0, stream>>>(Qb, Kb, Vb, mask, Ob);
    // out: M=8192, N=1024 -> 32 x 4 = 128 blocks (1/CU, half chip, one short round)
    gemm256<0><<<128, 512, 0, stream>>>(Ob, owb, out_b, out,
                                        nullptr, nullptr, nullptr, 8192, 1024, 1024, 4);
}

// Round 12
// 284.797 us; speedup vs baseline: 1.1021x; 1.1021x over previous
//
#include <hip/hip_runtime.h>
#include <stdint.h>
#include <type_traits>

// Problem constants
#define BB  4
#define SS  2048
#define DD  1024
#define HH  16
#define HDD 64

typedef __attribute__((ext_vector_type(8))) short s16x8;   // 8 bf16 (4 VGPRs)
typedef __attribute__((ext_vector_type(4))) float f32x4;   // MFMA C/D

__device__ inline short f2bf(float f) {
    union { float f; unsigned int u; } v; v.f = f;
    unsigned int r = (v.u + 0x7fffu + ((v.u >> 16) & 1u)) >> 16; // RNE
    return (short)r;
}

__device__ inline float bf2f(short s) {
    union { unsigned int u; float f; } v;
    v.u = ((unsigned int)(unsigned short)s) << 16;
    return v.f;
}

__device__ inline unsigned int pk2(float a, float b) {
    return (unsigned int)(unsigned short)f2bf(a) |
           ((unsigned int)(unsigned short)f2bf(b) << 16);
}

#define GLL(gp, lp) __builtin_amdgcn_global_load_lds( \
    (const __attribute__((address_space(1))) void*)(gp), \
    (__attribute__((address_space(3))) void*)(lp), 16, 0, 0)

// Raw barrier: orders this wave's LDS ops (lgkmcnt) then syncs. Does NOT
// drain vmcnt -> global_load_lds prefetch stays in flight across it.
__device__ inline void lds_barrier() {
    asm volatile("s_waitcnt lgkmcnt(0)" ::: "memory");
    __builtin_amdgcn_sched_barrier(0);
    __builtin_amdgcn_s_barrier();
    __builtin_amdgcn_sched_barrier(0);
}

// ---------------- fused fp32 -> bf16 cast of all three inputs ----------------
// x (8.39M) | qkv_w (3.15M) | out_w (1.05M) -> contiguous ws (xb|qwb|owb).
// All range boundaries are multiples of 2048 floats = one block's span, so the
// source-select branch is block-uniform. 6144 blocks exactly.
__global__ void cvt_all(const float* __restrict__ x, const float* __restrict__ qw,
                        const float* __restrict__ ow, short* __restrict__ dst) {
    const int X_N  = BB * SS * DD;          // 8388608
    const int QW_N = 3 * DD * DD;           // 3145728
    int i = (blockIdx.x * 256 + threadIdx.x) * 8;
    const float* s;
    if (i < X_N)            s = x + i;
    else if (i < X_N + QW_N) s = qw + (i - X_N);
    else                     s = ow + (i - X_N - QW_N);
    const float4* sp = (const float4*)s;
    float4 a = sp[0], b = sp[1];
    s16x8 o;
    o[0]=f2bf(a.x); o[1]=f2bf(a.y); o[2]=f2bf(a.z); o[3]=f2bf(a.w);
    o[4]=f2bf(b.x); o[5]=f2bf(b.y); o[6]=f2bf(b.z); o[7]=f2bf(b.w);
    *(s16x8*)(dst + i) = o;
}

// ---------------- GEMM C = A @ B^T + bias (BM=128 BN=128 BK=64, GLL dbuf) ----------
// Reverted to round-10 configuration (proven 96 µs qkv / ~33 µs out). 2-phase
// structural plateau for this shape (K=1024): both escape attempts (128x256
// 1-blk/CU r7; 8-phase port r11) regressed -> bank the known-good version.
template<int EPI>
__global__ __launch_bounds__(256, 2)
void gemm128(const short* __restrict__ A, const short* __restrict__ Bw,
             const float* __restrict__ bias, float* __restrict__ Cf,
             short* __restrict__ Qo, short* __restrict__ Ko, short* __restrict__ Vo,
             int M, int N, int K, int nbx)
{
    __shared__ short lsA[2][128 * 64];
    __shared__ short lsB[2][128 * 64];

    const int tid  = threadIdx.x;
    const int w    = tid >> 6, lane = tid & 63;
    const int quad = lane >> 4, l15 = lane & 15;
    const int wm = w >> 1, wn = w & 1;
    const int cpx = gridDim.x >> 3;
    const int swz = (blockIdx.x & 7) * cpx + (blockIdx.x >> 3);
    const int m0 = (swz / nbx) * 128, n0 = (swz % nbx) * 128;
    const int grow = lane >> 3;                 // row-within-octet this lane covers
    const int gcol = ((lane & 7) ^ grow) * 8;   // inverse-swizzled source col (shorts)
    const int l7 = l15 & 7;

    f32x4 acc[4][4] = {};

    auto issue = [&](int kt, int buf) {
#pragma unroll
        for (int jj = 0; jj < 4; ++jj) {        // A: 128 rows = 16 octets, 4/wave
            int row = w * 32 + jj * 8 + grow;
            GLL(A + (size_t)(m0 + row) * K + kt * 64 + gcol,
                &lsA[buf][(w * 4 + jj) * 512]);
        }
#pragma unroll
        for (int jj = 0; jj < 4; ++jj) {        // B: 128 rows = 16 octets, 4/wave
            int row = w * 32 + jj * 8 + grow;
            GLL(Bw + (size_t)(n0 + row) * K + kt * 64 + gcol,
                &lsB[buf][(w * 4 + jj) * 512]);
        }
    };

    const int NT = K >> 6;                      // BK=64 K-tiles
    issue(0, 0);
    for (int t = 0; t < NT; ++t) {
        const int buf = t & 1;
        lds_barrier();                          // A: all waves done reading buf^1
        if (t + 1 < NT) {
            issue(t + 1, buf ^ 1);
            asm volatile("s_waitcnt vmcnt(8)" ::: "memory");
        } else {
            asm volatile("s_waitcnt vmcnt(0)" ::: "memory");
        }
        __builtin_amdgcn_sched_barrier(0);
        __builtin_amdgcn_s_barrier();           // B: tile t fully staged (all waves)
        __builtin_amdgcn_sched_barrier(0);

        s16x8 af[4][2], bfr[4][2];
#pragma unroll
        for (int mf = 0; mf < 4; ++mf)
#pragma unroll
            for (int ks = 0; ks < 2; ++ks)
                af[mf][ks] = *(const s16x8*)&lsA[buf][(wm * 64 + mf * 16 + l15) * 64 +
                                                     (((ks * 4 + quad) ^ l7) * 8)];
#pragma unroll
        for (int nf = 0; nf < 4; ++nf)
#pragma unroll
            for (int ks = 0; ks < 2; ++ks)
                bfr[nf][ks] = *(const s16x8*)&lsB[buf][(wn * 64 + nf * 16 + l15) * 64 +
                                                      (((ks * 4 + quad) ^ l7) * 8)];

        __builtin_amdgcn_s_setprio(1);
#pragma unroll
        for (int ks = 0; ks < 2; ++ks)
#pragma unroll
            for (int mf = 0; mf < 4; ++mf)
#pragma unroll
                for (int nf = 0; nf < 4; ++nf)
                    acc[mf][nf] = __builtin_amdgcn_mfma_f32_16x16x32_bf16(
                                      af[mf][ks], bfr[nf][ks], acc[mf][nf], 0, 0, 0);
        __builtin_amdgcn_s_setprio(0);
    }

    if (EPI == 0) {
#pragma unroll
        for (int mf = 0; mf < 4; ++mf) {
            int row = m0 + wm * 64 + mf * 16 + quad * 4;
#pragma unroll
            for (int nf = 0; nf < 4; ++nf) {
                int col = n0 + wn * 64 + nf * 16 + l15;
                float bv = bias[col];
#pragma unroll
                for (int r = 0; r < 4; ++r)
                    Cf[(size_t)(row + r) * N + col] = acc[mf][nf][r] + bv;
            }
        }
    } else {
#pragma unroll
        for (int mf = 0; mf < 4; ++mf) {
            int row = m0 + wm * 64 + mf * 16 + quad * 4;
#pragma unroll
            for (int nf = 0; nf < 4; ++nf) {
                int col = n0 + wn * 64 + nf * 16 + l15;
                float bv = bias[col];
                int sel = col >> 10, h = (col >> 6) & 15, hd = col & 63;
#pragma unroll
                for (int r = 0; r < 4; ++r) {
                    int rr = row + r;
                    int b = rr >> 11, s = rr & 2047;
                    short val = f2bf(acc[mf][nf][r] + bv);
                    if (sel == 0)      Qo[(((size_t)b * HH + h) * SS + s) * HDD + hd] = val;
                    else if (sel == 1) Ko[(((size_t)b * HH + h) * SS + s) * HDD + hd] = val;
                    else               Vo[(((size_t)b * HH + h) * HDD + hd) * SS + s] = val;
                }
            }
        }
    }
}

// ---------------- causal flash attention (swapped QK^T + XCD-affinity remap) -------
// Round-10 kernel (swapped QK, in-lane softmax, counted vmcnt, 0 conflicts) with a
// bijective block remap so all 8 blocks sharing one (b,h)'s K/V land on the SAME
// XCD (linear%8 assumed round-robin; wrong assumption = perf-noise only).
// L = bx + 8*bh_raw; bh = (L&7)*8 + ((L>>3)&7); bx = L>>6. Per XCD: 8 bh x 512KB
// K/V = 4MB = L2 size; 64 blocks/XCD all resident -> K/V staged from L2 not L3/HBM.
__global__ __launch_bounds__(256, 2)
void attn_kernel(const short* __restrict__ Q, const short* __restrict__ Kb,
                 const short* __restrict__ Vb, const int* __restrict__ mask,
                 short* __restrict__ O)
{
    __shared__ short lsK[2][64 * 64];      // [buf][key][hd] linear (GLL), src-swizzled
    __shared__ short lsV[2][64 * 64];      // [buf][hd][key] linear (GLL), src-swizzled
    __shared__ short lsP[4][32 * 64];      // per-wave P [qrow 32][key 64], granule-XOR
    __shared__ short lsM[SS];              // mask additive, bf16 (0 or -1e30)

    const int tid  = threadIdx.x;
    const int w    = tid >> 6, lane = tid & 63;
    const int quad = lane >> 4, l15 = lane & 15;
    const int L  = blockIdx.x + 8 * blockIdx.y;      // [0,512)
    const int bx = L >> 6;                           // [0,8)
    const int bh = (L & 7) * 8 + ((L >> 3) & 7);     // [0,64), same-XCD groups
    const int b = bh >> 4;
    const size_t baseQK = (size_t)bh * SS * HDD;
    const size_t baseV  = (size_t)bh * HDD * SS;
    const float SC = 0.18033688f;          // (1/8) * log2(e)
    const int grow = lane >> 3;            // GLL: row-within-8 covered by this lane
    const int gcol = ((lane & 7) ^ grow) * 8;  // GLL: inverse-swizzled source col (shorts)
    const int l7 = l15 & 7;

    // stage mask -> lsM once (visible after first lds_barrier)
    {
        const int4* mp = (const int4*)(mask + b * SS);
        int4 a = mp[tid * 2], c = mp[tid * 2 + 1];
        const short NEG = f2bf(-1e30f);
        s16x8 mo;
        mo[0] = a.x ? (short)0 : NEG; mo[1] = a.y ? (short)0 : NEG;
        mo[2] = a.z ? (short)0 : NEG; mo[3] = a.w ? (short)0 : NEG;
        mo[4] = c.x ? (short)0 : NEG; mo[5] = c.y ? (short)0 : NEG;
        mo[6] = c.z ? (short)0 : NEG; mo[7] = c.w ? (short)0 : NEG;
        *(s16x8*)&lsM[tid * 8] = mo;
    }

    // issue tile (kv0) K/V global->LDS DMA into buffer buf: 4 GLL per wave
    auto issue = [&](int kv0, int buf) {
#pragma unroll
        for (int jj = 0; jj < 2; ++jj) {
            int row = w * 16 + jj * 8 + grow;                  // key row
            GLL(Kb + baseQK + (size_t)(kv0 + row) * HDD + gcol,
                &lsK[buf][(w * 2 + jj) * 512]);
        }
#pragma unroll
        for (int jj = 0; jj < 2; ++jj) {
            int row = w * 16 + jj * 8 + grow;                  // hd row
            GLL(Vb + baseV + (size_t)row * SS + kv0 + gcol,
                &lsV[buf][(w * 2 + jj) * 512]);
        }
    };

    for (int t = 0; t < 2; ++t) {
        const int qb = t ? bx : (15 - bx);  // heavy q-tile first
        const int q0 = qb * 128;
        const int qw0 = q0 + w * 32;        // this wave's first q-row

        s16x8 aq[2][2];
#pragma unroll
        for (int s = 0; s < 2; ++s)
#pragma unroll
            for (int ks = 0; ks < 2; ++ks)
                aq[s][ks] = *(const s16x8*)(Q + baseQK +
                    (size_t)(qw0 + s * 16 + l15) * HDD + ks * 32 + quad * 8);

        float m_r[2], l_r[2];
        f32x4 o_acc[2][4] = {};
#pragma unroll
        for (int s = 0; s < 2; ++s) { m_r[s] = -1e30f; l_r[s] = 0.f; }

        const int ntiles = 2 * qb + 2;      // 64-key tiles; last two are diagonal

        lds_barrier();                      // prev t's reads done / mask visible
        issue(0, 0);

        auto tile = [&](auto CC, int kv0, int buf, int kvn) {
            constexpr bool CAUS = decltype(CC)::value;

            lds_barrier();                  // A: all waves done reading buf^1
            if (kvn >= 0) issue(kvn, buf ^ 1);

            // mask additive: 4 consecutive k per nt (8B broadcast-friendly read)
            float madd[4][4];
#pragma unroll
            for (int nt = 0; nt < 4; ++nt) {
                uint2 mw4 = *(const uint2*)&lsM[kv0 + nt * 16 + quad * 4];
                madd[nt][0] = bf2f((short)(mw4.x & 0xffff));
                madd[nt][1] = bf2f((short)(mw4.x >> 16));
                madd[nt][2] = bf2f((short)(mw4.y & 0xffff));
                madd[nt][3] = bf2f((short)(mw4.y >> 16));
            }

            if (kvn >= 0) asm volatile("s_waitcnt vmcnt(4)" ::: "memory");
            else          asm volatile("s_waitcnt vmcnt(0)" ::: "memory");
            __builtin_amdgcn_sched_barrier(0);
            __builtin_amdgcn_s_barrier();   // B: all waves' GLLs for buf landed
            __builtin_amdgcn_sched_barrier(0);

            // S^T = K Q^T : D[key][q]; lane holds q=l15, key=kv0+nt*16+quad*4+r
            f32x4 sv[2][4];
#pragma unroll
            for (int s = 0; s < 2; ++s)
#pragma unroll
                for (int nt = 0; nt < 4; ++nt) sv[s][nt] = f32x4{};
#pragma unroll
            for (int ks = 0; ks < 2; ++ks)
#pragma unroll
                for (int nt = 0; nt < 4; ++nt) {
                    s16x8 kf = *(const s16x8*)&lsK[buf][(nt * 16 + l15) * 64 +
                                                       (((ks * 4 + quad) ^ l7) * 8)];
#pragma unroll
                    for (int s = 0; s < 2; ++s)
                        sv[s][nt] = __builtin_amdgcn_mfma_f32_16x16x32_bf16(
                                        kf, aq[s][ks], sv[s][nt], 0, 0, 0);
                }

            // scale + key-mask + causal (k now lane-indexed, q = l15)
#pragma unroll
            for (int s = 0; s < 2; ++s) {
                const int qg = qw0 + s * 16 + l15;
#pragma unroll
                for (int nt = 0; nt < 4; ++nt) {
                    const int kg0 = kv0 + nt * 16 + quad * 4;
#pragma unroll
                    for (int r = 0; r < 4; ++r) {
                        float scv = sv[s][nt][r] * SC + madd[nt][r];
                        if (CAUS && kg0 + r > qg) scv = -1e30f;
                        sv[s][nt][r] = scv;
                    }
                }
            }

            // row max over keys: 16 in-lane + cross-quad (2 shfl)
            float rm[2];
#pragma unroll
            for (int s = 0; s < 2; ++s) {
                float v = fmaxf(fmaxf(fmaxf(sv[s][0][0], sv[s][0][1]),
                                      fmaxf(sv[s][0][2], sv[s][0][3])),
                                fmaxf(fmaxf(sv[s][1][0], sv[s][1][1]),
                                      fmaxf(sv[s][1][2], sv[s][1][3])));
                float v2 = fmaxf(fmaxf(fmaxf(sv[s][2][0], sv[s][2][1]),
                                       fmaxf(sv[s][2][2], sv[s][2][3])),
                                 fmaxf(fmaxf(sv[s][3][0], sv[s][3][1]),
                                       fmaxf(sv[s][3][2], sv[s][3][3])));
                v = fmaxf(v, v2);
                v = fmaxf(v, __shfl_xor(v, 16));
                v = fmaxf(v, __shfl_xor(v, 32));
                rm[s] = v;
            }
            // T13 defer-max: rescale only when some row's max grew > 8 (log2 domain)
            float need = fmaxf(rm[0] - m_r[0], rm[1] - m_r[1]);
            if (!__all(need <= 8.0f)) {
#pragma unroll
                for (int s = 0; s < 2; ++s) {
                    float nm = fmaxf(m_r[s], rm[s]);
                    float al = __builtin_amdgcn_exp2f(m_r[s] - nm);
                    m_r[s] = nm;
                    l_r[s] *= al;
#pragma unroll
                    for (int r = 0; r < 4; ++r) {
                        float alq = __shfl(al, (quad << 2) + r + (lane & 48));
#pragma unroll
                        for (int ht = 0; ht < 4; ++ht)
                            o_acc[s][ht][r] *= alq;
                    }
                }
            }
            // P = exp2(S - m); per-lane partial l (cross-quad sum at epilogue)
#pragma unroll
            for (int s = 0; s < 2; ++s) {
                float rs = 0.f;
#pragma unroll
                for (int nt = 0; nt < 4; ++nt)
#pragma unroll
                    for (int r = 0; r < 4; ++r) {
                        float p = __builtin_amdgcn_exp2f(sv[s][nt][r] - m_r[s]);
                        sv[s][nt][r] = p;
                        rs += p;
                    }
                l_r[s] += rs;
            }

            // P -> wave-private buffer: 4 consecutive k per lane = 1 ds_write_b64
            // granule g8=(nt*2+(quad>>1))^(l15&7), half quad&1 == reader's (k2*4+quad)^l7
            short* lsPw = lsP[w];
#pragma unroll
            for (int s = 0; s < 2; ++s)
#pragma unroll
                for (int nt = 0; nt < 4; ++nt) {
                    uint2 pw;
                    pw.x = pk2(sv[s][nt][0], sv[s][nt][1]);
                    pw.y = pk2(sv[s][nt][2], sv[s][nt][3]);
                    int row = s * 16 + l15;
                    int g8 = (nt * 2 + (quad >> 1)) ^ l7;
                    *(uint2*)&lsPw[row * 64 + (g8 << 3) + ((quad & 1) << 2)] = pw;
                }
            asm volatile("s_waitcnt lgkmcnt(0)" ::: "memory");
            __builtin_amdgcn_sched_barrier(0);

            // O += P V (ap read identical to round 8; V read unchanged)
            s16x8 ap[2][2];
#pragma unroll
            for (int s = 0; s < 2; ++s)
#pragma unroll
                for (int k2 = 0; k2 < 2; ++k2)
                    ap[s][k2] = *(const s16x8*)&lsPw[(s * 16 + l15) * 64 +
                                                     (((k2 * 4 + quad) ^ l7) << 3)];
#pragma unroll
            for (int ht = 0; ht < 4; ++ht)
#pragma unroll
                for (int k2 = 0; k2 < 2; ++k2) {
                    s16x8 vf = *(const s16x8*)&lsV[buf][(ht * 16 + l15) * 64 +
                                                        (((k2 * 4 + quad) ^ l7) * 8)];
#pragma unroll
                    for (int s = 0; s < 2; ++s)
                        o_acc[s][ht] = __builtin_amdgcn_mfma_f32_16x16x32_bf16(
                                           ap[s][k2], vf, o_acc[s][ht], 0, 0, 0);
                }
        };

        for (int kt = 0; kt < ntiles; ++kt) {
            const int kvn = (kt + 1 < ntiles) ? (kt + 1) * 64 : -1;
            if (kt >= 2 * qb) tile(std::true_type{},  kt * 64, kt & 1, kvn);
            else              tile(std::false_type{}, kt * 64, kt & 1, kvn);
        }

        // epilogue: sum l across quads, redistribute to o_acc rows, write O
        const int hcol = (bh & 15) * HDD;
#pragma unroll
        for (int s = 0; s < 2; ++s) {
            float ls = l_r[s];
            ls += __shfl_xor(ls, 16);
            ls += __shfl_xor(ls, 32);      // full row-sum for q = l15
#pragma unroll
            for (int r = 0; r < 4; ++r) {
                float lq = __shfl(ls, (quad << 2) + r + (lane & 48));
                float inv = 1.0f / lq;
                int srow = qw0 + s * 16 + quad * 4 + r;
                size_t base = ((size_t)b * SS + srow) * DD + hcol;
#pragma unroll
                for (int ht = 0; ht < 4; ++ht)
                    O[base + ht * 16 + l15] = f2bf(o_acc[s][ht][r] * inv);
            }
        }
    }
}

// ---------------- launch ----------------
extern "C" void kernel_launch(void* const* d_in, const int* in_sizes, int n_in,
                              void* d_out, int out_size, void* d_ws, size_t ws_size,
                              hipStream_t stream) {
    const float* x     = (const float*)d_in[0];
    const int*   mask  = (const int*)d_in[1];
    const float* qkv_w = (const float*)d_in[2];
    const float* qkv_b = (const float*)d_in[3];
    const float* out_w = (const float*)d_in[4];
    const float* out_b = (const float*)d_in[5];
    float* out = (float*)d_out;

    const size_t M1 = (size_t)BB * SS;       // 8192
    short* ws  = (short*)d_ws;
    short* xb  = ws;
    short* qwb = xb  + M1 * DD;
    short* owb = qwb + (size_t)3 * DD * DD;
    short* Qb  = owb + (size_t)DD * DD;
    short* Kb  = Qb  + M1 * DD;
    short* Vb  = Kb  + M1 * DD;
    short* Ob  = Vb  + M1 * DD;

    // fused cast: (8192*1024 + 3*1024*1024 + 1024*1024) / 8 / 256 = 6144 blocks
    cvt_all<<<6144, 256, 0, stream>>>(x, qkv_w, out_w, ws);

    // qkv: M=8192, N=3072 -> 64 x 24 = 1536 blocks (2/CU x 3 exact rounds)
    gemm128<1><<<1536, 256, 0, stream>>>(xb, qwb, qkv_b, nullptr,
                                         Qb, Kb, Vb, 8192, 3072, 1024, 24);
    attn_kernel<<<dim3(8, BB * HH), 256, 0, stream>>>(Qb, Kb, Vb, mask, Ob);
    // out: M=8192, N=1024 -> 64 x 8 = 512 blocks (2/CU x 1 round)
    gemm128<0><<<512, 256, 0, stream>>>(Ob, owb, out_b, out,
                                        nullptr, nullptr, nullptr, 8192, 1024, 1024, 8);
}

// Round 13
// 284.385 us; speedup vs baseline: 1.1037x; 1.0014x over previous
//
#include <hip/hip_runtime.h>
#include <stdint.h>
#include <type_traits>

// Problem constants
#define BB  4
#define SS  2048
#define DD  1024
#define HH  16
#define HDD 64

typedef __attribute__((ext_vector_type(8))) short s16x8;   // 8 bf16 (4 VGPRs)
typedef __attribute__((ext_vector_type(4))) float f32x4;   // MFMA C/D

__device__ inline short f2bf(float f) {
    union { float f; unsigned int u; } v; v.f = f;
    unsigned int r = (v.u + 0x7fffu + ((v.u >> 16) & 1u)) >> 16; // RNE
    return (short)r;
}

__device__ inline float bf2f(short s) {
    union { unsigned int u; float f; } v;
    v.u = ((unsigned int)(unsigned short)s) << 16;
    return v.f;
}

__device__ inline unsigned int pk2(float a, float b) {
    return (unsigned int)(unsigned short)f2bf(a) |
           ((unsigned int)(unsigned short)f2bf(b) << 16);
}

#define GLL(gp, lp) __builtin_amdgcn_global_load_lds( \
    (const __attribute__((address_space(1))) void*)(gp), \
    (__attribute__((address_space(3))) void*)(lp), 16, 0, 0)

// Raw barrier: orders this wave's LDS ops (lgkmcnt) then syncs. Does NOT
// drain vmcnt -> global_load_lds prefetch stays in flight across it.
__device__ inline void lds_barrier() {
    asm volatile("s_waitcnt lgkmcnt(0)" ::: "memory");
    __builtin_amdgcn_sched_barrier(0);
    __builtin_amdgcn_s_barrier();
    __builtin_amdgcn_sched_barrier(0);
}

// ---------------- fused fp32 -> bf16 cast of all three inputs ----------------
// x (8.39M) | qkv_w (3.15M) | out_w (1.05M) -> contiguous ws (xb|qwb|owb).
// All range boundaries are multiples of one block's span -> block-uniform select.
__global__ void cvt_all(const float* __restrict__ x, const float* __restrict__ qw,
                        const float* __restrict__ ow, short* __restrict__ dst) {
    const int X_N  = BB * SS * DD;          // 8388608
    const int QW_N = 3 * DD * DD;           // 3145728
    int i = (blockIdx.x * 256 + threadIdx.x) * 8;
    const float* s;
    if (i < X_N)            s = x + i;
    else if (i < X_N + QW_N) s = qw + (i - X_N);
    else                     s = ow + (i - X_N - QW_N);
    const float4* sp = (const float4*)s;
    float4 a = sp[0], b = sp[1];
    s16x8 o;
    o[0]=f2bf(a.x); o[1]=f2bf(a.y); o[2]=f2bf(a.z); o[3]=f2bf(a.w);
    o[4]=f2bf(b.x); o[5]=f2bf(b.y); o[6]=f2bf(b.z); o[7]=f2bf(b.w);
    *(s16x8*)(dst + i) = o;
}

// ---------------- GEMM C = A @ B^T + bias (BM=BN=128, BK=32, TRIPLE buffer) --------
// r12 diagnosis: in the dbuf loop, vmcnt(8) waits on stage(t) issued only ONE
// iteration (~500cy) earlier = L3/HBM latency -> real stall every tile (MfmaUtil
// stuck at 21.5% across 4 structural variants). Fix WITHOUT touching the proven
// 2-barrier skeleton: 3 buffers, prefetch 2 tiles ahead. Iteration t:
//   barrier A (frees buf[(t+2)%3]; its readers (tile t-1) finished before A)
//   -> issue stage(t+2) (4 GLL) -> vmcnt(8) == {stage(t+1),stage(t+2)} in flight
//      -> passes with ~zero wait, while PROVING stage(t) (issued 2 iterations
//      ~1000cy ago) has landed -> barrier B -> 8 ds_read_b128 + 16 MFMA.
// Single vmcnt(0) only at the last tile. LDS 48 KB -> 3 blocks/CU (12 waves).
// Granule-XOR swizzle (g ^= row&3 for 32-col rows), both-sides (rule #21).
template<int EPI>
__global__ __launch_bounds__(256, 3)
void gemm128tb(const short* __restrict__ A, const short* __restrict__ Bw,
               const float* __restrict__ bias, float* __restrict__ Cf,
               short* __restrict__ Qo, short* __restrict__ Ko, short* __restrict__ Vo,
               int M, int N, int K, int nbx)
{
    __shared__ short lsA[3][128 * 32];
    __shared__ short lsB[3][128 * 32];

    const int tid  = threadIdx.x;
    const int w    = tid >> 6, lane = tid & 63;
    const int quad = lane >> 4, l15 = lane & 15;
    const int wm = w >> 1, wn = w & 1;
    const int cpx = gridDim.x >> 3;             // T1 XCD swizzle (grid % 8 == 0)
    const int swz = (blockIdx.x & 7) * cpx + (blockIdx.x >> 3);
    const int m0 = (swz / nbx) * 128, n0 = (swz % nbx) * 128;
    // GLL chunk = 16 rows x 32 cols (1024B). lane -> row16 = lane>>2, slot lane&3.
    const int grow = lane >> 2;                 // row-within-chunk this lane covers
    const int gcol = ((lane & 3) ^ (grow & 3)) * 8;  // inverse-swizzled src granule
    const int rsw = (l15 & 3);                  // reader XOR term (row&3 == l15&3)

    f32x4 acc[4][4] = {};

    auto issue = [&](int kt, int buf) {
#pragma unroll
        for (int jj = 0; jj < 2; ++jj) {        // A: 128 rows = 8 chunks, 2/wave
            int c = w * 2 + jj;
            GLL(A + (size_t)(m0 + c * 16 + grow) * K + kt * 32 + gcol,
                &lsA[buf][c * 512]);
        }
#pragma unroll
        for (int jj = 0; jj < 2; ++jj) {        // B: 128 rows = 8 chunks, 2/wave
            int c = w * 2 + jj;
            GLL(Bw + (size_t)(n0 + c * 16 + grow) * K + kt * 32 + gcol,
                &lsB[buf][c * 512]);
        }
    };

    const int NT = K >> 5;                      // BK=32 K-tiles (32 here)
    issue(0, 0);
    issue(1, 1);
    int buf = 0;                                // t % 3
    for (int t = 0; t < NT; ++t) {
        lds_barrier();                          // A: buf[(t+2)%3] readers (t-1) done
        const int nb2 = (buf + 2 >= 3) ? buf - 1 : buf + 2;   // (t+2)%3
        if (t + 2 < NT) {
            issue(t + 2, nb2);
            asm volatile("s_waitcnt vmcnt(8)" ::: "memory");   // stage(t) landed; ~free
        } else if (t + 1 < NT) {
            asm volatile("s_waitcnt vmcnt(4)" ::: "memory");
        } else {
            asm volatile("s_waitcnt vmcnt(0)" ::: "memory");
        }
        __builtin_amdgcn_sched_barrier(0);
        __builtin_amdgcn_s_barrier();           // B: tile t fully staged (all waves)
        __builtin_amdgcn_sched_barrier(0);

        s16x8 af[4], bfr[4];
#pragma unroll
        for (int mf = 0; mf < 4; ++mf)
            af[mf] = *(const s16x8*)&lsA[buf][(wm * 64 + mf * 16 + l15) * 32 +
                                             ((quad ^ rsw) * 8)];
#pragma unroll
        for (int nf = 0; nf < 4; ++nf)
            bfr[nf] = *(const s16x8*)&lsB[buf][(wn * 64 + nf * 16 + l15) * 32 +
                                              ((quad ^ rsw) * 8)];

        __builtin_amdgcn_s_setprio(1);
#pragma unroll
        for (int mf = 0; mf < 4; ++mf)
#pragma unroll
            for (int nf = 0; nf < 4; ++nf)
                acc[mf][nf] = __builtin_amdgcn_mfma_f32_16x16x32_bf16(
                                  af[mf], bfr[nf], acc[mf][nf], 0, 0, 0);
        __builtin_amdgcn_s_setprio(0);

        buf = (buf + 1 >= 3) ? 0 : buf + 1;
    }

    if (EPI == 0) {
#pragma unroll
        for (int mf = 0; mf < 4; ++mf) {
            int row = m0 + wm * 64 + mf * 16 + quad * 4;
#pragma unroll
            for (int nf = 0; nf < 4; ++nf) {
                int col = n0 + wn * 64 + nf * 16 + l15;
                float bv = bias[col];
#pragma unroll
                for (int r = 0; r < 4; ++r)
                    Cf[(size_t)(row + r) * N + col] = acc[mf][nf][r] + bv;
            }
        }
    } else {
#pragma unroll
        for (int mf = 0; mf < 4; ++mf) {
            int row = m0 + wm * 64 + mf * 16 + quad * 4;
#pragma unroll
            for (int nf = 0; nf < 4; ++nf) {
                int col = n0 + wn * 64 + nf * 16 + l15;
                float bv = bias[col];
                int sel = col >> 10, h = (col >> 6) & 15, hd = col & 63;
#pragma unroll
                for (int r = 0; r < 4; ++r) {
                    int rr = row + r;
                    int b = rr >> 11, s = rr & 2047;
                    short val = f2bf(acc[mf][nf][r] + bv);
                    if (sel == 0)      Qo[(((size_t)b * HH + h) * SS + s) * HDD + hd] = val;
                    else if (sel == 1) Ko[(((size_t)b * HH + h) * SS + s) * HDD + hd] = val;
                    else               Vo[(((size_t)b * HH + h) * HDD + hd) * SS + s] = val;
                }
            }
        }
    }
}

// ---------------- causal flash attention (swapped QK^T + XCD-affinity remap) -------
// (unchanged from round 12)
__global__ __launch_bounds__(256, 2)
void attn_kernel(const short* __restrict__ Q, const short* __restrict__ Kb,
                 const short* __restrict__ Vb, const int* __restrict__ mask,
                 short* __restrict__ O)
{
    __shared__ short lsK[2][64 * 64];      // [buf][key][hd] linear (GLL), src-swizzled
    __shared__ short lsV[2][64 * 64];      // [buf][hd][key] linear (GLL), src-swizzled
    __shared__ short lsP[4][32 * 64];      // per-wave P [qrow 32][key 64], granule-XOR
    __shared__ short lsM[SS];              // mask additive, bf16 (0 or -1e30)

    const int tid  = threadIdx.x;
    const int w    = tid >> 6, lane = tid & 63;
    const int quad = lane >> 4, l15 = lane & 15;
    const int L  = blockIdx.x + 8 * blockIdx.y;      // [0,512)
    const int bx = L >> 6;                           // [0,8)
    const int bh = (L & 7) * 8 + ((L >> 3) & 7);     // [0,64), same-XCD groups
    const int b = bh >> 4;
    const size_t baseQK = (size_t)bh * SS * HDD;
    const size_t baseV  = (size_t)bh * HDD * SS;
    const float SC = 0.18033688f;          // (1/8) * log2(e)
    const int grow = lane >> 3;            // GLL: row-within-8 covered by this lane
    const int gcol = ((lane & 7) ^ grow) * 8;  // GLL: inverse-swizzled source col (shorts)
    const int l7 = l15 & 7;

    // stage mask -> lsM once (visible after first lds_barrier)
    {
        const int4* mp = (const int4*)(mask + b * SS);
        int4 a = mp[tid * 2], c = mp[tid * 2 + 1];
        const short NEG = f2bf(-1e30f);
        s16x8 mo;
        mo[0] = a.x ? (short)0 : NEG; mo[1] = a.y ? (short)0 : NEG;
        mo[2] = a.z ? (short)0 : NEG; mo[3] = a.w ? (short)0 : NEG;
        mo[4] = c.x ? (short)0 : NEG; mo[5] = c.y ? (short)0 : NEG;
        mo[6] = c.z ? (short)0 : NEG; mo[7] = c.w ? (short)0 : NEG;
        *(s16x8*)&lsM[tid * 8] = mo;
    }

    // issue tile (kv0) K/V global->LDS DMA into buffer buf: 4 GLL per wave
    auto issue = [&](int kv0, int buf) {
#pragma unroll
        for (int jj = 0; jj < 2; ++jj) {
            int row = w * 16 + jj * 8 + grow;                  // key row
            GLL(Kb + baseQK + (size_t)(kv0 + row) * HDD + gcol,
                &lsK[buf][(w * 2 + jj) * 512]);
        }
#pragma unroll
        for (int jj = 0; jj < 2; ++jj) {
            int row = w * 16 + jj * 8 + grow;                  // hd row
            GLL(Vb + baseV + (size_t)row * SS + kv0 + gcol,
                &lsV[buf][(w * 2 + jj) * 512]);
        }
    };

    for (int t = 0; t < 2; ++t) {
        const int qb = t ? bx : (15 - bx);  // heavy q-tile first
        const int q0 = qb * 128;
        const int qw0 = q0 + w * 32;        // this wave's first q-row

        s16x8 aq[2][2];
#pragma unroll
        for (int s = 0; s < 2; ++s)
#pragma unroll
            for (int ks = 0; ks < 2; ++ks)
                aq[s][ks] = *(const s16x8*)(Q + baseQK +
                    (size_t)(qw0 + s * 16 + l15) * HDD + ks * 32 + quad * 8);

        float m_r[2], l_r[2];
        f32x4 o_acc[2][4] = {};
#pragma unroll
        for (int s = 0; s < 2; ++s) { m_r[s] = -1e30f; l_r[s] = 0.f; }

        const int ntiles = 2 * qb + 2;      // 64-key tiles; last two are diagonal

        lds_barrier();                      // prev t's reads done / mask visible
        issue(0, 0);

        auto tile = [&](auto CC, int kv0, int buf, int kvn) {
            constexpr bool CAUS = decltype(CC)::value;

            lds_barrier();                  // A: all waves done reading buf^1
            if (kvn >= 0) issue(kvn, buf ^ 1);

            // mask additive: 4 consecutive k per nt (8B broadcast-friendly read)
            float madd[4][4];
#pragma unroll
            for (int nt = 0; nt < 4; ++nt) {
                uint2 mw4 = *(const uint2*)&lsM[kv0 + nt * 16 + quad * 4];
                madd[nt][0] = bf2f((short)(mw4.x & 0xffff));
                madd[nt][1] = bf2f((short)(mw4.x >> 16));
                madd[nt][2] = bf2f((short)(mw4.y & 0xffff));
                madd[nt][3] = bf2f((short)(mw4.y >> 16));
            }

            if (kvn >= 0) asm volatile("s_waitcnt vmcnt(4)" ::: "memory");
            else          asm volatile("s_waitcnt vmcnt(0)" ::: "memory");
            __builtin_amdgcn_sched_barrier(0);
            __builtin_amdgcn_s_barrier();   // B: all waves' GLLs for buf landed
            __builtin_amdgcn_sched_barrier(0);

            // S^T = K Q^T : D[key][q]; lane holds q=l15, key=kv0+nt*16+quad*4+r
            f32x4 sv[2][4];
#pragma unroll
            for (int s = 0; s < 2; ++s)
#pragma unroll
                for (int nt = 0; nt < 4; ++nt) sv[s][nt] = f32x4{};
#pragma unroll
            for (int ks = 0; ks < 2; ++ks)
#pragma unroll
                for (int nt = 0; nt < 4; ++nt) {
                    s16x8 kf = *(const s16x8*)&lsK[buf][(nt * 16 + l15) * 64 +
                                                       (((ks * 4 + quad) ^ l7) * 8)];
#pragma unroll
                    for (int s = 0; s < 2; ++s)
                        sv[s][nt] = __builtin_amdgcn_mfma_f32_16x16x32_bf16(
                                        kf, aq[s][ks], sv[s][nt], 0, 0, 0);
                }

            // scale + key-mask + causal (k lane-indexed, q = l15)
#pragma unroll
            for (int s = 0; s < 2; ++s) {
                const int qg = qw0 + s * 16 + l15;
#pragma unroll
                for (int nt = 0; nt < 4; ++nt) {
                    const int kg0 = kv0 + nt * 16 + quad * 4;
#pragma unroll
                    for (int r = 0; r < 4; ++r) {
                        float scv = sv[s][nt][r] * SC + madd[nt][r];
                        if (CAUS && kg0 + r > qg) scv = -1e30f;
                        sv[s][nt][r] = scv;
                    }
                }
            }

            // row max over keys: 16 in-lane + cross-quad (2 shfl)
            float rm[2];
#pragma unroll
            for (int s = 0; s < 2; ++s) {
                float v = fmaxf(fmaxf(fmaxf(sv[s][0][0], sv[s][0][1]),
                                      fmaxf(sv[s][0][2], sv[s][0][3])),
                                fmaxf(fmaxf(sv[s][1][0], sv[s][1][1]),
                                      fmaxf(sv[s][1][2], sv[s][1][3])));
                float v2 = fmaxf(fmaxf(fmaxf(sv[s][2][0], sv[s][2][1]),
                                       fmaxf(sv[s][2][2], sv[s][2][3])),
                                 fmaxf(fmaxf(sv[s][3][0], sv[s][3][1]),
                                       fmaxf(sv[s][3][2], sv[s][3][3])));
                v = fmaxf(v, v2);
                v = fmaxf(v, __shfl_xor(v, 16));
                v = fmaxf(v, __shfl_xor(v, 32));
                rm[s] = v;
            }
            // T13 defer-max: rescale only when some row's max grew > 8 (log2 domain)
            float need = fmaxf(rm[0] - m_r[0], rm[1] - m_r[1]);
            if (!__all(need <= 8.0f)) {
#pragma unroll
                for (int s = 0; s < 2; ++s) {
                    float nm = fmaxf(m_r[s], rm[s]);
                    float al = __builtin_amdgcn_exp2f(m_r[s] - nm);
                    m_r[s] = nm;
                    l_r[s] *= al;
#pragma unroll
                    for (int r = 0; r < 4; ++r) {
                        float alq = __shfl(al, (quad << 2) + r + (lane & 48));
#pragma unroll
                        for (int ht = 0; ht < 4; ++ht)
                            o_acc[s][ht][r] *= alq;
                    }
                }
            }
            // P = exp2(S - m); per-lane partial l (cross-quad sum at epilogue)
#pragma unroll
            for (int s = 0; s < 2; ++s) {
                float rs = 0.f;
#pragma unroll
                for (int nt = 0; nt < 4; ++nt)
#pragma unroll
                    for (int r = 0; r < 4; ++r) {
                        float p = __builtin_amdgcn_exp2f(sv[s][nt][r] - m_r[s]);
                        sv[s][nt][r] = p;
                        rs += p;
                    }
                l_r[s] += rs;
            }

            // P -> wave-private buffer: 4 consecutive k per lane = 1 ds_write_b64
            short* lsPw = lsP[w];
#pragma unroll
            for (int s = 0; s < 2; ++s)
#pragma unroll
                for (int nt = 0; nt < 4; ++nt) {
                    uint2 pw;
                    pw.x = pk2(sv[s][nt][0], sv[s][nt][1]);
                    pw.y = pk2(sv[s][nt][2], sv[s][nt][3]);
                    int row = s * 16 + l15;
                    int g8 = (nt * 2 + (quad >> 1)) ^ l7;
                    *(uint2*)&lsPw[row * 64 + (g8 << 3) + ((quad & 1) << 2)] = pw;
                }
            asm volatile("s_waitcnt lgkmcnt(0)" ::: "memory");
            __builtin_amdgcn_sched_barrier(0);

            // O += P V
            s16x8 ap[2][2];
#pragma unroll
            for (int s = 0; s < 2; ++s)
#pragma unroll
                for (int k2 = 0; k2 < 2; ++k2)
                    ap[s][k2] = *(const s16x8*)&lsPw[(s * 16 + l15) * 64 +
                                                     (((k2 * 4 + quad) ^ l7) << 3)];
#pragma unroll
            for (int ht = 0; ht < 4; ++ht)
#pragma unroll
                for (int k2 = 0; k2 < 2; ++k2) {
                    s16x8 vf = *(const s16x8*)&lsV[buf][(ht * 16 + l15) * 64 +
                                                        (((k2 * 4 + quad) ^ l7) * 8)];
#pragma unroll
                    for (int s = 0; s < 2; ++s)
                        o_acc[s][ht] = __builtin_amdgcn_mfma_f32_16x16x32_bf16(
                                           ap[s][k2], vf, o_acc[s][ht], 0, 0, 0);
                }
        };

        for (int kt = 0; kt < ntiles; ++kt) {
            const int kvn = (kt + 1 < ntiles) ? (kt + 1) * 64 : -1;
            if (kt >= 2 * qb) tile(std::true_type{},  kt * 64, kt & 1, kvn);
            else              tile(std::false_type{}, kt * 64, kt & 1, kvn);
        }

        // epilogue: sum l across quads, redistribute to o_acc rows, write O
        const int hcol = (bh & 15) * HDD;
#pragma unroll
        for (int s = 0; s < 2; ++s) {
            float ls = l_r[s];
            ls += __shfl_xor(ls, 16);
            ls += __shfl_xor(ls, 32);      // full row-sum for q = l15
#pragma unroll
            for (int r = 0; r < 4; ++r) {
                float lq = __shfl(ls, (quad << 2) + r + (lane & 48));
                float inv = 1.0f / lq;
                int srow = qw0 + s * 16 + quad * 4 + r;
                size_t base = ((size_t)b * SS + srow) * DD + hcol;
#pragma unroll
                for (int ht = 0; ht < 4; ++ht)
                    O[base + ht * 16 + l15] = f2bf(o_acc[s][ht][r] * inv);
            }
        }
    }
}

// ---------------- launch ----------------
extern "C" void kernel_launch(void* const* d_in, const int* in_sizes, int n_in,
                              void* d_out, int out_size, void* d_ws, size_t ws_size,
                              hipStream_t stream) {
    const float* x     = (const float*)d_in[0];
    const int*   mask  = (const int*)d_in[1];
    const float* qkv_w = (const float*)d_in[2];
    const float* qkv_b = (const float*)d_in[3];
    const float* out_w = (const float*)d_in[4];
    const float* out_b = (const float*)d_in[5];
    float* out = (float*)d_out;

    const size_t M1 = (size_t)BB * SS;       // 8192
    short* ws  = (short*)d_ws;
    short* xb  = ws;
    short* qwb = xb  + M1 * DD;
    short* owb = qwb + (size_t)3 * DD * DD;
    short* Qb  = owb + (size_t)DD * DD;
    short* Kb  = Qb  + M1 * DD;
    short* Vb  = Kb  + M1 * DD;
    short* Ob  = Vb  + M1 * DD;

    // fused cast: (8192*1024 + 3*1024*1024 + 1024*1024) / 8 / 256 = 6144 blocks
    cvt_all<<<6144, 256, 0, stream>>>(x, qkv_w, out_w, ws);

    // qkv: M=8192, N=3072 -> 64 x 24 = 1536 blocks (3/CU by LDS)
    gemm128tb<1><<<1536, 256, 0, stream>>>(xb, qwb, qkv_b, nullptr,
                                           Qb, Kb, Vb, 8192, 3072, 1024, 24);
    attn_kernel<<<dim3(8, BB * HH), 256, 0, stream>>>(Qb, Kb, Vb, mask, Ob);
    // out: M=8192, N=1024 -> 64 x 8 = 512 blocks
    gemm128tb<0><<<512, 256, 0, stream>>>(Ob, owb, out_b, out,
                                          nullptr, nullptr, nullptr, 8192, 1024, 1024, 8);
}